// Round 11
// baseline (458.323 us; speedup 1.0000x reference)
//
#include <hip/hip_runtime.h>

// GraphConvolution: out = A_coo @ (x @ W)
// x: [100000, 256] f32, W: [256, 64] f32, A: 1.6M edges (rows, cols int32, vals f32)
//
// R9 -> R10: both LDS-tiled GEMMs stalled 75-80% (VALUBusy*dur ~= 21us FMA
// floor in R8 AND R9; barriers + low blocks/CU). New gemm: one thread = one
// row, acc[64] in VGPRs, x streamed via prefetched float4s, W read via
// UNIFORM index -> s_load + FMA-with-SGPR. Zero LDS, zero barriers, 1563
// independent 64-thread blocks. Scatter pipeline unchanged (R8-proven).
// (R10 resubmission: prior round hit GPUAcquisitionTimeout, never measured.)

#define KDIM 256
#define MDIM 64
#define BSHIFT 7              // 128 rows per bucket
#define BMAX 1024             // max buckets supported by LDS tables
#define FCAP 6500             // fine_scatter LDS staging capacity (records)

// ---------------------------------------------------------------- GEMM
// One thread per output row; 64-thread blocks for fine-grained CU balance.
__global__ __launch_bounds__(64) void gemm_xw(
    const float* __restrict__ x, const float* __restrict__ W,
    float* __restrict__ support, int nrows)
{
    const int row_raw = blockIdx.x * 64 + threadIdx.x;
    const int row = min(row_raw, nrows - 1);      // clamp: keep flow uniform
    const float4* xr = reinterpret_cast<const float4*>(x + (size_t)row * KDIM);

    float acc[MDIM];
    #pragma unroll
    for (int f = 0; f < MDIM; ++f) acc[f] = 0.f;

    float4 xa0 = xr[0], xa1 = xr[1], xa2 = xr[2], xa3 = xr[3];

    #pragma unroll 1
    for (int kt = 0; kt < KDIM; kt += 16) {
        // prefetch next 16-k chunk of this row while computing current
        float4 xb0, xb1, xb2, xb3;
        if (kt + 16 < KDIM) {
            const int nq = (kt >> 2) + 4;
            xb0 = xr[nq + 0]; xb1 = xr[nq + 1];
            xb2 = xr[nq + 2]; xb3 = xr[nq + 3];
        }
        #pragma unroll
        for (int q = 0; q < 4; ++q) {
            const float4 xv = (q == 0) ? xa0 : (q == 1) ? xa1 :
                              (q == 2) ? xa2 : xa3;
            #pragma unroll
            for (int j = 0; j < 4; ++j) {
                const float xk = (j == 0) ? xv.x : (j == 1) ? xv.y :
                                 (j == 2) ? xv.z : xv.w;
                // W row address is uniform across lanes -> scalar loads,
                // FMA consumes the SGPR operand directly.
                const float* wrow = &W[(size_t)(kt + q * 4 + j) * MDIM];
                #pragma unroll
                for (int f = 0; f < MDIM; ++f)
                    acc[f] = fmaf(xk, wrow[f], acc[f]);
            }
        }
        xa0 = xb0; xa1 = xb1; xa2 = xb2; xa3 = xb3;
    }

    if (row_raw < nrows) {
        float4* o = reinterpret_cast<float4*>(support + (size_t)row * MDIM);
        #pragma unroll
        for (int q = 0; q < 16; ++q)
            o[q] = make_float4(acc[q * 4 + 0], acc[q * 4 + 1],
                               acc[q * 4 + 2], acc[q * 4 + 3]);
    }
}

// ------------------------------------------------- coarse bucket build
__global__ __launch_bounds__(256) void coarse_hist(
    const int* __restrict__ rows, int* __restrict__ counts,
    int nedges, int nbuckets)
{
    __shared__ int lb[BMAX];
    const int t = threadIdx.x;
    for (int i = t; i < nbuckets; i += 256) lb[i] = 0;
    __syncthreads();
    int e = blockIdx.x * 256 + t;
    const int stride = gridDim.x * 256;
    for (; e < nedges; e += stride)
        atomicAdd(&lb[rows[e] >> BSHIFT], 1);
    __syncthreads();
    for (int i = t; i < nbuckets; i += 256) {
        int c = lb[i];
        if (c) atomicAdd(&counts[i], c);
    }
}

// Single-block exclusive scan (n <= 1024): offsets + cursor seed.
__global__ __launch_bounds__(256) void coarse_scan(
    const int* __restrict__ counts, int* __restrict__ offsets,
    int* __restrict__ cursor, int n)
{
    __shared__ int sh[256];
    const int t = threadIdx.x;
    const int base = t * 4;
    int v0 = 0, v1 = 0, v2 = 0, v3 = 0;
    if (base + 0 < n) v0 = counts[base + 0];
    if (base + 1 < n) v1 = counts[base + 1];
    if (base + 2 < n) v2 = counts[base + 2];
    if (base + 3 < n) v3 = counts[base + 3];
    const int tsum = v0 + v1 + v2 + v3;
    sh[t] = tsum;
    __syncthreads();
    for (int off = 1; off < 256; off <<= 1) {
        int xv = (t >= off) ? sh[t - off] : 0;
        __syncthreads();
        sh[t] += xv;
        __syncthreads();
    }
    int excl = sh[t] - tsum;
    if (base + 0 < n) { offsets[base + 0] = excl; cursor[base + 0] = excl; } excl += v0;
    if (base + 1 < n) { offsets[base + 1] = excl; cursor[base + 1] = excl; } excl += v1;
    if (base + 2 < n) { offsets[base + 2] = excl; cursor[base + 2] = excl; } excl += v2;
    if (base + 3 < n) { offsets[base + 3] = excl; cursor[base + 3] = excl; }
}

// Block-chunk reservation scatter into coarse buckets.
// Packed record: pk.x = col(17b) | rowlow(7b)<<17 ; pk.y = val bits.
__global__ __launch_bounds__(256) void bin_edges(
    const int* __restrict__ rows, const int* __restrict__ cols,
    const float* __restrict__ vals, int* __restrict__ cursor,
    int2* __restrict__ edata, int nedges, int nbuckets)
{
    __shared__ int lb[BMAX];
    const int t = threadIdx.x;
    const int per = (nedges + gridDim.x - 1) / gridDim.x;
    const int e0 = blockIdx.x * per;
    const int e1 = min(e0 + per, nedges);

    for (int i = t; i < nbuckets; i += 256) lb[i] = 0;
    __syncthreads();
    for (int e = e0 + t; e < e1; e += 256)
        atomicAdd(&lb[rows[e] >> BSHIFT], 1);
    __syncthreads();
    for (int i = t; i < nbuckets; i += 256) {
        int c = lb[i];
        lb[i] = c ? atomicAdd(&cursor[i], c) : 0;   // lb becomes block cursor
    }
    __syncthreads();
    for (int e = e0 + t; e < e1; e += 256) {
        const int r = rows[e];
        const int pos = atomicAdd(&lb[r >> BSHIFT], 1);
        int2 pk;
        pk.x = (cols[e] & 0x1FFFF) | ((r & 127) << 17);
        pk.y = __float_as_int(vals[e]);
        edata[pos] = pk;
    }
}

// ------------------------------------------------- per-bucket fine sort
__global__ __launch_bounds__(256) void fine_scatter(
    const int* __restrict__ offsets, const int* __restrict__ counts,
    int2* __restrict__ edata, int* __restrict__ foff, int* __restrict__ fcnt,
    int* __restrict__ bflag, int nrows)
{
    __shared__ int2 lrec[FCAP];      // 52 KB
    __shared__ int cnt[128];
    __shared__ int cur[128];
    __shared__ int sh[128];
    const int t = threadIdx.x;
    const int b = blockIdx.x;
    const int beg = offsets[b];
    const int cntE = counts[b];
    const int row0 = b << BSHIFT;

    if (t < 128) cnt[t] = 0;
    __syncthreads();

    if (cntE > FCAP) {
        if (t == 0) bflag[b] = 1;
        if (t < 128) {
            const int grow = row0 + t;
            if (grow < nrows) { foff[grow] = beg; fcnt[grow] = 0; }
        }
        return;
    }

    for (int k = t; k < cntE; k += 256) {
        int2 p = edata[beg + k];
        lrec[k] = p;
        atomicAdd(&cnt[(p.x >> 17) & 127], 1);
    }
    __syncthreads();

    if (t < 128) sh[t] = cnt[t];
    __syncthreads();
    for (int off = 1; off < 128; off <<= 1) {
        int xv = 0;
        if (t < 128 && t >= off) xv = sh[t - off];
        __syncthreads();
        if (t < 128) sh[t] += xv;
        __syncthreads();
    }
    if (t < 128) {
        const int excl = sh[t] - cnt[t];
        cur[t] = excl;
        const int grow = row0 + t;
        if (grow < nrows) { foff[grow] = beg + excl; fcnt[grow] = cnt[t]; }
    }
    __syncthreads();

    for (int k = t; k < cntE; k += 256) {
        const int2 p = lrec[k];
        const int rl = (p.x >> 17) & 127;
        const int pos = beg + atomicAdd(&cur[rl], 1);
        edata[pos] = make_int2(p.x & 0x1FFFF, p.y);
    }
}

// ---------------------------------------------------------- SpMM reduce
// One 16-lane group per row; lane owns 4 features. Register accumulate,
// 8-deep unroll for gather MLP.
__global__ __launch_bounds__(256) void spmm_reduce(
    const int* __restrict__ foff, const int* __restrict__ fcnt,
    const int2* __restrict__ edata, const float* __restrict__ support,
    float* __restrict__ out, int nrows)
{
    const int g = blockIdx.x * 16 + (threadIdx.x >> 4);
    const int f0 = (threadIdx.x & 15) * 4;
    if (g >= nrows) return;
    int e = foff[g];
    const int end = e + fcnt[g];
    float ax = 0.f, ay = 0.f, az = 0.f, aw = 0.f;

    for (; e + 8 <= end; e += 8) {
        int2 p[8];
        #pragma unroll
        for (int u = 0; u < 8; ++u) p[u] = edata[e + u];
        float4 s[8];
        #pragma unroll
        for (int u = 0; u < 8; ++u)
            s[u] = *reinterpret_cast<const float4*>(
                       &support[(size_t)p[u].x * MDIM + f0]);
        #pragma unroll
        for (int u = 0; u < 8; ++u) {
            const float v = __int_as_float(p[u].y);
            ax = fmaf(v, s[u].x, ax); ay = fmaf(v, s[u].y, ay);
            az = fmaf(v, s[u].z, az); aw = fmaf(v, s[u].w, aw);
        }
    }
    for (; e < end; ++e) {
        const int2 p = edata[e];
        const float v = __int_as_float(p.y);
        float4 s = *reinterpret_cast<const float4*>(
                       &support[(size_t)p.x * MDIM + f0]);
        ax = fmaf(v, s.x, ax); ay = fmaf(v, s.y, ay);
        az = fmaf(v, s.z, az); aw = fmaf(v, s.w, aw);
    }
    *reinterpret_cast<float4*>(&out[(size_t)g * MDIM + f0]) =
        make_float4(ax, ay, az, aw);
}

// --------------------------------------- oversized-bucket atomic tail
__global__ __launch_bounds__(256) void scatter_tail(
    const int* __restrict__ offsets, const int* __restrict__ counts,
    const int* __restrict__ bflag, const int2* __restrict__ edata,
    const float* __restrict__ support, float* __restrict__ out)
{
    const int b = blockIdx.x;
    if (!bflag[b]) return;
    const int beg = offsets[b];
    const int end = beg + counts[b];
    const int row0 = b << BSHIFT;
    const int g  = threadIdx.x >> 4;
    const int f0 = (threadIdx.x & 15) * 4;
    for (int e = beg + g; e < end; e += 16) {
        const int2 p = edata[e];
        const int c = p.x & 0x1FFFF;
        const int r = row0 + ((p.x >> 17) & 127);
        const float v = __int_as_float(p.y);
        float4 s = *reinterpret_cast<const float4*>(
                       &support[(size_t)c * MDIM + f0]);
        float* op = &out[(size_t)r * MDIM + f0];
        atomicAdd(op + 0, v * s.x);
        atomicAdd(op + 1, v * s.y);
        atomicAdd(op + 2, v * s.z);
        atomicAdd(op + 3, v * s.w);
    }
}

// ----------------------------------------------- fallback atomic scatter
__global__ __launch_bounds__(256) void scatter_edges(
    const int* __restrict__ rows, const int* __restrict__ cols,
    const float* __restrict__ vals, const float* __restrict__ support,
    float* __restrict__ out, int nedges)
{
    const int t = blockIdx.x * blockDim.x + threadIdx.x;
    const int fq = (t & 15) * 4;
    int e = t >> 4;
    const int estride = (gridDim.x * blockDim.x) >> 4;
    for (; e < nedges; e += estride) {
        const int r = rows[e];
        const int c = cols[e];
        const float v = vals[e];
        float4 s = *reinterpret_cast<const float4*>(
                       &support[(size_t)c * MDIM + fq]);
        float* op = &out[(size_t)r * MDIM + fq];
        atomicAdd(op + 0, v * s.x);
        atomicAdd(op + 1, v * s.y);
        atomicAdd(op + 2, v * s.z);
        atomicAdd(op + 3, v * s.w);
    }
}

// ---------------------------------------------------------------- launch
extern "C" void kernel_launch(void* const* d_in, const int* in_sizes, int n_in,
                              void* d_out, int out_size, void* d_ws, size_t ws_size,
                              hipStream_t stream) {
    const float* x    = (const float*)d_in[0];
    const int*   rows = (const int*)d_in[1];
    const int*   cols = (const int*)d_in[2];
    const float* vals = (const float*)d_in[3];
    const float* W    = (const float*)d_in[4];
    float* out = (float*)d_out;

    const int nnodes = in_sizes[0] / KDIM;   // 100000
    const int nedges = in_sizes[1];          // 1600000
    const int nbuckets = (nnodes + 127) >> BSHIFT;   // 782

    auto align256 = [](size_t v) { return (v + 255) & ~(size_t)255; };
    const size_t sz_support = align256((size_t)nnodes * MDIM * 4);
    const size_t sz_bkt     = align256((size_t)BMAX * 4);
    const size_t sz_nodes   = align256((size_t)nnodes * 4);
    const size_t sz_edata   = align256((size_t)nedges * 8);
    const size_t need = sz_support + 4 * sz_bkt + 2 * sz_nodes + sz_edata;

    char* w = (char*)d_ws;
    float* support = (float*)w;  w += sz_support;

    gemm_xw<<<dim3((nnodes + 63) / 64), dim3(64), 0, stream>>>(
        x, W, support, nnodes);

    // col packing needs nnodes <= 2^17; bucket tables need nbuckets <= BMAX.
    if (ws_size >= need && nbuckets <= BMAX && nnodes <= (1 << 17)) {
        int* counts  = (int*)w;  w += sz_bkt;
        int* offsets = (int*)w;  w += sz_bkt;
        int* cursor  = (int*)w;  w += sz_bkt;
        int* bflag   = (int*)w;  w += sz_bkt;
        int* foff    = (int*)w;  w += sz_nodes;
        int* fcnt    = (int*)w;  w += sz_nodes;
        int2* edata  = (int2*)w;

        hipMemsetAsync(counts, 0, (size_t)nbuckets * 4, stream);
        hipMemsetAsync(bflag, 0, (size_t)nbuckets * 4, stream);

        coarse_hist<<<dim3(256), dim3(256), 0, stream>>>(
            rows, counts, nedges, nbuckets);
        coarse_scan<<<dim3(1), dim3(256), 0, stream>>>(
            counts, offsets, cursor, nbuckets);
        bin_edges<<<dim3(256), dim3(256), 0, stream>>>(
            rows, cols, vals, cursor, edata, nedges, nbuckets);
        fine_scatter<<<dim3(nbuckets), dim3(256), 0, stream>>>(
            offsets, counts, edata, foff, fcnt, bflag, nnodes);
        spmm_reduce<<<dim3((nnodes + 15) / 16), dim3(256), 0, stream>>>(
            foff, fcnt, edata, support, out, nnodes);
        scatter_tail<<<dim3(nbuckets), dim3(256), 0, stream>>>(
            offsets, counts, bflag, edata, support, out);
    } else {
        hipMemsetAsync(d_out, 0, (size_t)out_size * sizeof(float), stream);
        scatter_edges<<<dim3(4096), dim3(256), 0, stream>>>(
            rows, cols, vals, support, out, nedges);
    }
}

// Round 12
// 347.669 us; speedup vs baseline: 1.3183x; 1.3183x over previous
//
#include <hip/hip_runtime.h>

// GraphConvolution: out = A_coo @ (x @ W)
// x: [100000, 256] f32, W: [256, 64] f32, A: 1.6M edges (rows, cols int32, vals f32)
//
// R11 -> R12: register-direct GEMM failed (181us, VALUBusy 12%: W-row s_loads
// serialize, SGPR budget holds only 1 row ahead, 1 wave/block can't hide it).
// Revert to R8's proven 128x64 LDS tile (97us best measured) with ONE change:
// BK 64->32 halves LDS to 24KB -> 6 blocks/CU capacity (was 1.6 resident at
// 48KB), so co-resident blocks hide each other's barrier drains.
// Scatter pipeline unchanged (R8-proven).

#define KDIM 256
#define MDIM 64
#define BSHIFT 7              // 128 rows per bucket
#define BMAX 1024             // max buckets supported by LDS tables
#define FCAP 6500             // fine_scatter LDS staging capacity (records)

// ---------------------------------------------------------------- GEMM
// Block tile 128 rows x 64 feats, K-tile 32. Thread tile 8 rows x 4 feats.
// xs staged with col-group XOR swizzle: 16-lane groups broadcast (same addr),
// tr groups hit distinct bank quads (R8 measured 0 conflicts).
__global__ __launch_bounds__(256, 4) void gemm_xw(
    const float* __restrict__ x, const float* __restrict__ W,
    float* __restrict__ support, int nrows)
{
    __shared__ float xs[128][32];   // 16 KB
    __shared__ float ws2[32][64];   // 8 KB; ws2[kk][f]
    const int tid = threadIdx.x;
    const int tr  = tid >> 4;        // 0..15 row-group
    const int f0  = (tid & 15) * 4;  // feature base
    const int swz = tr & 3;
    const int row0 = blockIdx.x * 128;

    float acc[8][4];
    #pragma unroll
    for (int i = 0; i < 8; ++i)
        #pragma unroll
        for (int j = 0; j < 4; ++j) acc[i][j] = 0.f;

    for (int kt = 0; kt < KDIM; kt += 32) {
        __syncthreads();
        // stage x tile: 128 rows x 8 float4-slots = 1024 slots, 4/thread
        #pragma unroll
        for (int i = 0; i < 4; ++i) {
            int slot = tid + i * 256;
            int r = slot >> 3;        // row in tile
            int q = slot & 7;         // float4 within row
            int grow = row0 + r;
            float4 v = make_float4(0.f, 0.f, 0.f, 0.f);
            if (grow < nrows)
                v = *reinterpret_cast<const float4*>(
                        &x[(size_t)grow * KDIM + kt + q * 4]);
            int qs = q ^ ((r >> 3) & 3);
            *reinterpret_cast<float4*>(&xs[r][qs * 4]) = v;
        }
        // stage W tile: 32 kk x 16 float4-slots = 512 slots, 2/thread
        #pragma unroll
        for (int i = 0; i < 2; ++i) {
            int slot = tid + i * 256;
            int kk = slot >> 4;
            int q = slot & 15;
            float4 v = *reinterpret_cast<const float4*>(
                           &W[(size_t)(kt + kk) * MDIM + q * 4]);
            *reinterpret_cast<float4*>(&ws2[kk][q * 4]) = v;
        }
        __syncthreads();

        #pragma unroll 2
        for (int kk = 0; kk < 32; kk += 4) {
            const int q4 = kk >> 2;
            float4 xv[8];
            #pragma unroll
            for (int i = 0; i < 8; ++i)
                xv[i] = *reinterpret_cast<const float4*>(
                            &xs[tr * 8 + i][(q4 ^ swz) * 4]);
            #pragma unroll
            for (int k2 = 0; k2 < 4; ++k2) {
                float4 wv = *reinterpret_cast<const float4*>(&ws2[kk + k2][f0]);
                #pragma unroll
                for (int i = 0; i < 8; ++i) {
                    const float xk = (k2 == 0) ? xv[i].x :
                                     (k2 == 1) ? xv[i].y :
                                     (k2 == 2) ? xv[i].z : xv[i].w;
                    acc[i][0] = fmaf(xk, wv.x, acc[i][0]);
                    acc[i][1] = fmaf(xk, wv.y, acc[i][1]);
                    acc[i][2] = fmaf(xk, wv.z, acc[i][2]);
                    acc[i][3] = fmaf(xk, wv.w, acc[i][3]);
                }
            }
        }
    }

    #pragma unroll
    for (int i = 0; i < 8; ++i) {
        int grow = row0 + tr * 8 + i;
        if (grow < nrows) {
            float4 v = make_float4(acc[i][0], acc[i][1], acc[i][2], acc[i][3]);
            *reinterpret_cast<float4*>(&support[(size_t)grow * MDIM + f0]) = v;
        }
    }
}

// ------------------------------------------------- coarse bucket build
__global__ __launch_bounds__(256) void coarse_hist(
    const int* __restrict__ rows, int* __restrict__ counts,
    int nedges, int nbuckets)
{
    __shared__ int lb[BMAX];
    const int t = threadIdx.x;
    for (int i = t; i < nbuckets; i += 256) lb[i] = 0;
    __syncthreads();
    int e = blockIdx.x * 256 + t;
    const int stride = gridDim.x * 256;
    for (; e < nedges; e += stride)
        atomicAdd(&lb[rows[e] >> BSHIFT], 1);
    __syncthreads();
    for (int i = t; i < nbuckets; i += 256) {
        int c = lb[i];
        if (c) atomicAdd(&counts[i], c);
    }
}

// Single-block exclusive scan (n <= 1024): offsets + cursor seed.
__global__ __launch_bounds__(256) void coarse_scan(
    const int* __restrict__ counts, int* __restrict__ offsets,
    int* __restrict__ cursor, int n)
{
    __shared__ int sh[256];
    const int t = threadIdx.x;
    const int base = t * 4;
    int v0 = 0, v1 = 0, v2 = 0, v3 = 0;
    if (base + 0 < n) v0 = counts[base + 0];
    if (base + 1 < n) v1 = counts[base + 1];
    if (base + 2 < n) v2 = counts[base + 2];
    if (base + 3 < n) v3 = counts[base + 3];
    const int tsum = v0 + v1 + v2 + v3;
    sh[t] = tsum;
    __syncthreads();
    for (int off = 1; off < 256; off <<= 1) {
        int xv = (t >= off) ? sh[t - off] : 0;
        __syncthreads();
        sh[t] += xv;
        __syncthreads();
    }
    int excl = sh[t] - tsum;
    if (base + 0 < n) { offsets[base + 0] = excl; cursor[base + 0] = excl; } excl += v0;
    if (base + 1 < n) { offsets[base + 1] = excl; cursor[base + 1] = excl; } excl += v1;
    if (base + 2 < n) { offsets[base + 2] = excl; cursor[base + 2] = excl; } excl += v2;
    if (base + 3 < n) { offsets[base + 3] = excl; cursor[base + 3] = excl; }
}

// Block-chunk reservation scatter into coarse buckets.
// Packed record: pk.x = col(17b) | rowlow(7b)<<17 ; pk.y = val bits.
__global__ __launch_bounds__(256) void bin_edges(
    const int* __restrict__ rows, const int* __restrict__ cols,
    const float* __restrict__ vals, int* __restrict__ cursor,
    int2* __restrict__ edata, int nedges, int nbuckets)
{
    __shared__ int lb[BMAX];
    const int t = threadIdx.x;
    const int per = (nedges + gridDim.x - 1) / gridDim.x;
    const int e0 = blockIdx.x * per;
    const int e1 = min(e0 + per, nedges);

    for (int i = t; i < nbuckets; i += 256) lb[i] = 0;
    __syncthreads();
    for (int e = e0 + t; e < e1; e += 256)
        atomicAdd(&lb[rows[e] >> BSHIFT], 1);
    __syncthreads();
    for (int i = t; i < nbuckets; i += 256) {
        int c = lb[i];
        lb[i] = c ? atomicAdd(&cursor[i], c) : 0;   // lb becomes block cursor
    }
    __syncthreads();
    for (int e = e0 + t; e < e1; e += 256) {
        const int r = rows[e];
        const int pos = atomicAdd(&lb[r >> BSHIFT], 1);
        int2 pk;
        pk.x = (cols[e] & 0x1FFFF) | ((r & 127) << 17);
        pk.y = __float_as_int(vals[e]);
        edata[pos] = pk;
    }
}

// ------------------------------------------------- per-bucket fine sort
__global__ __launch_bounds__(256) void fine_scatter(
    const int* __restrict__ offsets, const int* __restrict__ counts,
    int2* __restrict__ edata, int* __restrict__ foff, int* __restrict__ fcnt,
    int* __restrict__ bflag, int nrows)
{
    __shared__ int2 lrec[FCAP];      // 52 KB
    __shared__ int cnt[128];
    __shared__ int cur[128];
    __shared__ int sh[128];
    const int t = threadIdx.x;
    const int b = blockIdx.x;
    const int beg = offsets[b];
    const int cntE = counts[b];
    const int row0 = b << BSHIFT;

    if (t < 128) cnt[t] = 0;
    __syncthreads();

    if (cntE > FCAP) {
        if (t == 0) bflag[b] = 1;
        if (t < 128) {
            const int grow = row0 + t;
            if (grow < nrows) { foff[grow] = beg; fcnt[grow] = 0; }
        }
        return;
    }

    for (int k = t; k < cntE; k += 256) {
        int2 p = edata[beg + k];
        lrec[k] = p;
        atomicAdd(&cnt[(p.x >> 17) & 127], 1);
    }
    __syncthreads();

    if (t < 128) sh[t] = cnt[t];
    __syncthreads();
    for (int off = 1; off < 128; off <<= 1) {
        int xv = 0;
        if (t < 128 && t >= off) xv = sh[t - off];
        __syncthreads();
        if (t < 128) sh[t] += xv;
        __syncthreads();
    }
    if (t < 128) {
        const int excl = sh[t] - cnt[t];
        cur[t] = excl;
        const int grow = row0 + t;
        if (grow < nrows) { foff[grow] = beg + excl; fcnt[grow] = cnt[t]; }
    }
    __syncthreads();

    for (int k = t; k < cntE; k += 256) {
        const int2 p = lrec[k];
        const int rl = (p.x >> 17) & 127;
        const int pos = beg + atomicAdd(&cur[rl], 1);
        edata[pos] = make_int2(p.x & 0x1FFFF, p.y);
    }
}

// ---------------------------------------------------------- SpMM reduce
// One 16-lane group per row; lane owns 4 features. Register accumulate,
// 8-deep unroll for gather MLP.
__global__ __launch_bounds__(256) void spmm_reduce(
    const int* __restrict__ foff, const int* __restrict__ fcnt,
    const int2* __restrict__ edata, const float* __restrict__ support,
    float* __restrict__ out, int nrows)
{
    const int g = blockIdx.x * 16 + (threadIdx.x >> 4);
    const int f0 = (threadIdx.x & 15) * 4;
    if (g >= nrows) return;
    int e = foff[g];
    const int end = e + fcnt[g];
    float ax = 0.f, ay = 0.f, az = 0.f, aw = 0.f;

    for (; e + 8 <= end; e += 8) {
        int2 p[8];
        #pragma unroll
        for (int u = 0; u < 8; ++u) p[u] = edata[e + u];
        float4 s[8];
        #pragma unroll
        for (int u = 0; u < 8; ++u)
            s[u] = *reinterpret_cast<const float4*>(
                       &support[(size_t)p[u].x * MDIM + f0]);
        #pragma unroll
        for (int u = 0; u < 8; ++u) {
            const float v = __int_as_float(p[u].y);
            ax = fmaf(v, s[u].x, ax); ay = fmaf(v, s[u].y, ay);
            az = fmaf(v, s[u].z, az); aw = fmaf(v, s[u].w, aw);
        }
    }
    for (; e < end; ++e) {
        const int2 p = edata[e];
        const float v = __int_as_float(p.y);
        float4 s = *reinterpret_cast<const float4*>(
                       &support[(size_t)p.x * MDIM + f0]);
        ax = fmaf(v, s.x, ax); ay = fmaf(v, s.y, ay);
        az = fmaf(v, s.z, az); aw = fmaf(v, s.w, aw);
    }
    *reinterpret_cast<float4*>(&out[(size_t)g * MDIM + f0]) =
        make_float4(ax, ay, az, aw);
}

// --------------------------------------- oversized-bucket atomic tail
__global__ __launch_bounds__(256) void scatter_tail(
    const int* __restrict__ offsets, const int* __restrict__ counts,
    const int* __restrict__ bflag, const int2* __restrict__ edata,
    const float* __restrict__ support, float* __restrict__ out)
{
    const int b = blockIdx.x;
    if (!bflag[b]) return;
    const int beg = offsets[b];
    const int end = beg + counts[b];
    const int row0 = b << BSHIFT;
    const int g  = threadIdx.x >> 4;
    const int f0 = (threadIdx.x & 15) * 4;
    for (int e = beg + g; e < end; e += 16) {
        const int2 p = edata[e];
        const int c = p.x & 0x1FFFF;
        const int r = row0 + ((p.x >> 17) & 127);
        const float v = __int_as_float(p.y);
        float4 s = *reinterpret_cast<const float4*>(
                       &support[(size_t)c * MDIM + f0]);
        float* op = &out[(size_t)r * MDIM + f0];
        atomicAdd(op + 0, v * s.x);
        atomicAdd(op + 1, v * s.y);
        atomicAdd(op + 2, v * s.z);
        atomicAdd(op + 3, v * s.w);
    }
}

// ----------------------------------------------- fallback atomic scatter
__global__ __launch_bounds__(256) void scatter_edges(
    const int* __restrict__ rows, const int* __restrict__ cols,
    const float* __restrict__ vals, const float* __restrict__ support,
    float* __restrict__ out, int nedges)
{
    const int t = blockIdx.x * blockDim.x + threadIdx.x;
    const int fq = (t & 15) * 4;
    int e = t >> 4;
    const int estride = (gridDim.x * blockDim.x) >> 4;
    for (; e < nedges; e += estride) {
        const int r = rows[e];
        const int c = cols[e];
        const float v = vals[e];
        float4 s = *reinterpret_cast<const float4*>(
                       &support[(size_t)c * MDIM + fq]);
        float* op = &out[(size_t)r * MDIM + fq];
        atomicAdd(op + 0, v * s.x);
        atomicAdd(op + 1, v * s.y);
        atomicAdd(op + 2, v * s.z);
        atomicAdd(op + 3, v * s.w);
    }
}

// ---------------------------------------------------------------- launch
extern "C" void kernel_launch(void* const* d_in, const int* in_sizes, int n_in,
                              void* d_out, int out_size, void* d_ws, size_t ws_size,
                              hipStream_t stream) {
    const float* x    = (const float*)d_in[0];
    const int*   rows = (const int*)d_in[1];
    const int*   cols = (const int*)d_in[2];
    const float* vals = (const float*)d_in[3];
    const float* W    = (const float*)d_in[4];
    float* out = (float*)d_out;

    const int nnodes = in_sizes[0] / KDIM;   // 100000
    const int nedges = in_sizes[1];          // 1600000
    const int nbuckets = (nnodes + 127) >> BSHIFT;   // 782

    auto align256 = [](size_t v) { return (v + 255) & ~(size_t)255; };
    const size_t sz_support = align256((size_t)nnodes * MDIM * 4);
    const size_t sz_bkt     = align256((size_t)BMAX * 4);
    const size_t sz_nodes   = align256((size_t)nnodes * 4);
    const size_t sz_edata   = align256((size_t)nedges * 8);
    const size_t need = sz_support + 4 * sz_bkt + 2 * sz_nodes + sz_edata;

    char* w = (char*)d_ws;
    float* support = (float*)w;  w += sz_support;

    gemm_xw<<<dim3((nnodes + 127) / 128), dim3(256), 0, stream>>>(
        x, W, support, nnodes);

    // col packing needs nnodes <= 2^17; bucket tables need nbuckets <= BMAX.
    if (ws_size >= need && nbuckets <= BMAX && nnodes <= (1 << 17)) {
        int* counts  = (int*)w;  w += sz_bkt;
        int* offsets = (int*)w;  w += sz_bkt;
        int* cursor  = (int*)w;  w += sz_bkt;
        int* bflag   = (int*)w;  w += sz_bkt;
        int* foff    = (int*)w;  w += sz_nodes;
        int* fcnt    = (int*)w;  w += sz_nodes;
        int2* edata  = (int2*)w;

        hipMemsetAsync(counts, 0, (size_t)nbuckets * 4, stream);
        hipMemsetAsync(bflag, 0, (size_t)nbuckets * 4, stream);

        coarse_hist<<<dim3(256), dim3(256), 0, stream>>>(
            rows, counts, nedges, nbuckets);
        coarse_scan<<<dim3(1), dim3(256), 0, stream>>>(
            counts, offsets, cursor, nbuckets);
        bin_edges<<<dim3(256), dim3(256), 0, stream>>>(
            rows, cols, vals, cursor, edata, nedges, nbuckets);
        fine_scatter<<<dim3(nbuckets), dim3(256), 0, stream>>>(
            offsets, counts, edata, foff, fcnt, bflag, nnodes);
        spmm_reduce<<<dim3((nnodes + 15) / 16), dim3(256), 0, stream>>>(
            foff, fcnt, edata, support, out, nnodes);
        scatter_tail<<<dim3(nbuckets), dim3(256), 0, stream>>>(
            offsets, counts, bflag, edata, support, out);
    } else {
        hipMemsetAsync(d_out, 0, (size_t)out_size * sizeof(float), stream);
        scatter_edges<<<dim3(4096), dim3(256), 0, stream>>>(
            rows, cols, vals, support, out, nedges);
    }
}